// Round 2
// baseline (1459.893 us; speedup 1.0000x reference)
//
#include <hip/hip_runtime.h>

#define VV 6890
#define N3 20670      // V*3
#define NT 162        // ceil(N3/128)
#define NKC 7         // K chunks of 32 (K=224)
#define NJOUT 61
#define OUTJ ((size_t)1024*VV*3)

// ws layout: floats JT[72]@0, JS[720]@72, A(rel transforms f32 1024*288)@1024;
// bytes: Ablk bf16 @1183744 (448KB), Bblk bf16 @1642496 (9.29MB)
#define WS_JT 0
#define WS_JS 72
#define WS_A  1024
#define WS_ABLK_BYTES 1183744
#define WS_BBLK_BYTES 1642496

typedef float f32x4 __attribute__((ext_vector_type(4)));
typedef short bf16x8 __attribute__((ext_vector_type(8)));

__constant__ int c_par[24] = {-1,0,0,0,1,2,3,4,5,6,7,8,9,9,9,12,13,14,16,17,18,19,20,21};

__device__ __forceinline__ short f2bf(float x) {
    union { float f; unsigned u; } v; v.f = x;
    unsigned r = (v.u + 0x7fffu + ((v.u >> 16) & 1u)) >> 16;
    return (short)r;
}

// ---- K0a: build tiled/transposed/swizzled bf16 B matrix [nt][kc][col 128][k 32] ----
// logical B[k][n]: k<207 -> posedirs[k][n]; 207<=k<217 -> shapedirs[n/3][n%3][k-207]; else 0
// within tile: col c's 64B row holds k-groups hi=0..3 (16B each) at slot (hi ^ ((c>>1)&3))
__global__ __launch_bounds__(256) void k_buildB(
    const float* __restrict__ pd, const float* __restrict__ sd, short* __restrict__ Bblk)
{
    const int nt = blockIdx.x, kc = blockIdx.y;
    const int tid = threadIdx.x;
    __shared__ float T[32][129];
    for (int idx = tid; idx < 4096; idx += 256) {
        const int kl = idx >> 7, c = idx & 127;
        const int kg = kc*32 + kl;
        const int n = nt*128 + c;
        float val = 0.f;
        if (n < N3) {
            if (kg < 207) val = pd[(size_t)kg*N3 + n];
            else if (kg < 217) val = sd[(size_t)(n/3)*30 + (n%3)*10 + (kg-207)];
        }
        T[kl][c] = val;
    }
    __syncthreads();
    short* tile = Bblk + (size_t)(nt*NKC + kc)*4096;
#pragma unroll
    for (int t = 0; t < 2; t++) {
        const int s = tid*2 + t;          // 16B slot index 0..511
        const int c = s >> 2;
        const int hi = (s & 3) ^ ((c >> 1) & 3);   // logical k-group stored at this slot
        bf16x8 pk;
#pragma unroll
        for (int e = 0; e < 8; e++) pk[e] = f2bf(T[hi*8+e][c]);
        *(bf16x8*)(tile + s*8) = pk;
    }
}

// ---- K0b: JT = Jreg@v_template, JS = Jreg@shapedirs (exact f32) ----
__global__ __launch_bounds__(256) void k_jointreg(
    const float* __restrict__ Jreg, const float* __restrict__ vt,
    const float* __restrict__ sd, float* __restrict__ ws)
{
    const int j = blockIdx.x / 3, k = blockIdx.x % 3;
    float acc[11];
#pragma unroll
    for (int i = 0; i < 11; i++) acc[i] = 0.f;
    for (int v = threadIdx.x; v < VV; v += 256) {
        const float jr = Jreg[j*VV + v];
        acc[0] += jr * vt[v*3 + k];
        const float* s = sd + (size_t)v*30 + k*10;
#pragma unroll
        for (int l = 0; l < 10; l++) acc[1+l] += jr * s[l];
    }
#pragma unroll
    for (int off = 1; off < 64; off <<= 1)
#pragma unroll
        for (int i = 0; i < 11; i++) acc[i] += __shfl_xor(acc[i], off);
    __shared__ float red[4][11];
    const int wv = threadIdx.x >> 6, ln = threadIdx.x & 63;
    if (ln == 0)
#pragma unroll
        for (int i = 0; i < 11; i++) red[wv][i] = acc[i];
    __syncthreads();
    if (threadIdx.x == 0) {
        ws[WS_JT + j*3 + k] = red[0][0]+red[1][0]+red[2][0]+red[3][0];
#pragma unroll
        for (int l = 0; l < 10; l++)
            ws[WS_JS + (j*3+k)*10 + l] = red[0][1+l]+red[1][1+l]+red[2][1+l]+red[3][1+l];
    }
}

// ---- K1: rodrigues + chain + rel transforms (f32) + bf16 A-matrix + joints[0:24] ----
__global__ __launch_bounds__(64) void k_batch(
    const float* __restrict__ betas, const float* __restrict__ poses,
    float* __restrict__ ws, short* __restrict__ Ablk, float* __restrict__ out)
{
    const int b = blockIdx.x, lane = threadIdx.x;
    __shared__ float R[24][9], Jr[24][3], RJ[24][3], G[24][12];
    if (lane < 24) {
        const int j = lane;
        const float x = poses[b*72 + j*3 + 0];
        const float y = poses[b*72 + j*3 + 1];
        const float z = poses[b*72 + j*3 + 2];
        const float xe = x + 1e-8f, ye = y + 1e-8f, ze = z + 1e-8f;
        const float ang = sqrtf(xe*xe + ye*ye + ze*ze);
        const float inv = 1.0f / ang;
        const float rx = x*inv, ry = y*inv, rz = z*inv;
        const float sn = sinf(ang), cs = cosf(ang);
        const float K[9] = {0.f,-rz,ry, rz,0.f,-rx, -ry,rx,0.f};
        float Rl[9];
#pragma unroll
        for (int r = 0; r < 3; r++)
#pragma unroll
            for (int c = 0; c < 3; c++) {
                float kk = 0.f;
#pragma unroll
                for (int m = 0; m < 3; m++) kk += K[r*3+m]*K[m*3+c];
                Rl[r*3+c] = ((r==c)?1.f:0.f) + sn*K[r*3+c] + (1.f-cs)*kk;
            }
#pragma unroll
        for (int e = 0; e < 9; e++) R[j][e] = Rl[e];
#pragma unroll
        for (int k = 0; k < 3; k++) {
            float a = ws[WS_JT + j*3 + k];
#pragma unroll
            for (int l = 0; l < 10; l++) a += betas[b*10 + l] * ws[WS_JS + (j*3+k)*10 + l];
            Jr[j][k] = a;
        }
    }
    __syncthreads();
    // bf16 A-matrix row (224 wide): [pose_feature(207) | betas(10) | zeros]
    {
        const int r = b & 127, mt = b >> 7;
        const int sw = (r >> 1) & 3;
        for (int k = lane; k < 224; k += 64) {
            float val;
            if (k < 207) { const int j = k/9 + 1, e = k - (j-1)*9;
                           val = R[j][e] - ((e==0||e==4||e==8)?1.f:0.f); }
            else if (k < 217) val = betas[b*10 + (k-207)];
            else val = 0.f;
            const int kc = k >> 5, hi = (k >> 3) & 3;
            Ablk[(size_t)(mt*NKC + kc)*4096 + r*32 + ((hi ^ sw)*8) + (k & 7)] = f2bf(val);
        }
    }
    if (lane < 24) {
        const int j = lane, p = c_par[j];
#pragma unroll
        for (int k = 0; k < 3; k++) RJ[j][k] = (j == 0) ? Jr[0][k] : (Jr[j][k] - Jr[p][k]);
    }
    __syncthreads();
    if (lane < 12) {
        const int r = lane >> 2, c = lane & 3;
        G[0][lane] = (c < 3) ? R[0][r*3+c] : RJ[0][r];
    }
    __syncthreads();
    for (int i = 1; i < 24; i++) {
        float val = 0.f;
        if (lane < 12) {
            const int r = lane >> 2, c = lane & 3, p = c_par[i];
            if (c < 3)
                val = G[p][r*4+0]*R[i][0+c] + G[p][r*4+1]*R[i][3+c] + G[p][r*4+2]*R[i][6+c];
            else
                val = G[p][r*4+0]*RJ[i][0] + G[p][r*4+1]*RJ[i][1] + G[p][r*4+2]*RJ[i][2] + G[p][r*4+3];
        }
        __syncthreads();
        if (lane < 12) G[i][lane] = val;
        __syncthreads();
    }
    if (lane < 24)
#pragma unroll
        for (int k = 0; k < 3; k++)
            out[OUTJ + ((size_t)b*NJOUT + lane)*3 + k] = G[lane][k*4+3];
    for (int e = lane; e < 288; e += 64) {
        const int j = e / 12, rc = e % 12, r = rc >> 2, c = rc & 3;
        float val = G[j][rc];
        if (c == 3)
            val -= G[j][r*4+0]*Jr[j][0] + G[j][r*4+1]*Jr[j][1] + G[j][r*4+2]*Jr[j][2];
        ws[WS_A + (size_t)b*288 + e] = val;
    }
}

// ---- K2: bf16 MFMA GEMM (1024 x 20670 x 224) -> v_posed (f32) into out verts region ----
__global__ __launch_bounds__(256) void k_gemm(
    const short* __restrict__ Ablk, const short* __restrict__ Bblk,
    const float* __restrict__ vt, float* __restrict__ out)
{
    const int nt = blockIdx.x, mt = blockIdx.y;
    const int tid = threadIdx.x;
    const int lane = tid & 63, wid = tid >> 6;
    const int wm = wid >> 1, wn = wid & 1;
    __shared__ float4 SM4[1024] __attribute__((aligned(16)));   // A: [0..511], B: [512..1023]
    short* SMs = (short*)SM4;

    f32x4 acc[4][4];
#pragma unroll
    for (int m = 0; m < 4; m++)
#pragma unroll
        for (int n = 0; n < 4; n++) acc[m][n] = (f32x4){0.f,0.f,0.f,0.f};

    const int hi = lane >> 4;
    int aoff[4], boff[4];
#pragma unroll
    for (int m = 0; m < 4; m++) {
        const int r = wm*64 + m*16 + (lane & 15);
        aoff[m] = r*32 + ((hi ^ ((r >> 1) & 3)) * 8);
    }
#pragma unroll
    for (int n = 0; n < 4; n++) {
        const int c = wn*64 + n*16 + (lane & 15);
        boff[n] = 4096 + c*32 + ((hi ^ ((c >> 1) & 3)) * 8);
    }
    const float4* gA = (const float4*)(Ablk + (size_t)mt*NKC*4096);
    const float4* gB = (const float4*)(Bblk + (size_t)nt*NKC*4096);

    for (int kc = 0; kc < NKC; kc++) {
        __syncthreads();
        SM4[tid]       = gA[kc*512 + tid];
        SM4[tid + 256] = gA[kc*512 + tid + 256];
        SM4[tid + 512] = gB[kc*512 + tid];
        SM4[tid + 768] = gB[kc*512 + tid + 256];
        __syncthreads();
        bf16x8 af[4], bfr[4];
#pragma unroll
        for (int m = 0; m < 4; m++) af[m] = *(const bf16x8*)&SMs[aoff[m]];
#pragma unroll
        for (int n = 0; n < 4; n++) bfr[n] = *(const bf16x8*)&SMs[boff[n]];
#pragma unroll
        for (int m = 0; m < 4; m++)
#pragma unroll
            for (int n = 0; n < 4; n++)
                acc[m][n] = __builtin_amdgcn_mfma_f32_16x16x32_bf16(af[m], bfr[n], acc[m][n], 0, 0, 0);
    }
#pragma unroll
    for (int n = 0; n < 4; n++) {
        const int gcol = nt*128 + wn*64 + n*16 + (lane & 15);
        if (gcol < N3) {
            const float vtv = vt[gcol];
#pragma unroll
            for (int m = 0; m < 4; m++) {
                const int row0 = mt*128 + wm*64 + m*16 + (lane >> 4)*4;
#pragma unroll
                for (int rg = 0; rg < 4; rg++)
                    out[(size_t)(row0+rg)*N3 + gcol] = acc[m][n][rg] + vtv;
            }
        }
    }
}

// ---- K3: LBS, in-place on out verts (each (b,v) owned by exactly one thread) ----
__global__ __launch_bounds__(256) void k_lbs(
    const float* __restrict__ Ag, const float* __restrict__ lbsw, float* __restrict__ out)
{
    const int v0 = blockIdx.x * 64, b0 = blockIdx.y * 32;
    const int tid = threadIdx.x;
    const int vg = tid & 15, bg = tid >> 4;
    __shared__ float As[32*288];
    __shared__ float Ws[64*25];
    for (int i = tid; i < 9216; i += 256) As[i] = Ag[(size_t)b0*288 + i];
    for (int i = tid; i < 1536; i += 256) {
        const int r = i / 24, c = i % 24;
        const int v = v0 + r;
        Ws[r*25 + c] = (v < VV) ? lbsw[(size_t)v*24 + c] : 0.f;
    }
    __syncthreads();
    float u[2][4][3], vo[2][4][3];
#pragma unroll
    for (int bi = 0; bi < 2; bi++)
#pragma unroll
        for (int vi = 0; vi < 4; vi++) {
            const int v = v0 + vi*16 + vg;
            const int vc = (v < VV) ? v : VV-1;
            const size_t base = (size_t)(b0 + bg*2 + bi)*N3 + (size_t)vc*3;
#pragma unroll
            for (int k = 0; k < 3; k++) { u[bi][vi][k] = out[base+k]; vo[bi][vi][k] = 0.f; }
        }
#pragma unroll
    for (int bi = 0; bi < 2; bi++) {
        const float* arow = As + (bg*2+bi)*288;
        for (int j = 0; j < 24; j++) {
            const float4 a0 = *(const float4*)(arow + j*12);
            const float4 a1 = *(const float4*)(arow + j*12 + 4);
            const float4 a2 = *(const float4*)(arow + j*12 + 8);
#pragma unroll
            for (int vi = 0; vi < 4; vi++) {
                const float w = Ws[(vi*16+vg)*25 + j];
                const float ux = u[bi][vi][0], uy = u[bi][vi][1], uz = u[bi][vi][2];
                vo[bi][vi][0] += w * (a0.x*ux + a0.y*uy + a0.z*uz + a0.w);
                vo[bi][vi][1] += w * (a1.x*ux + a1.y*uy + a1.z*uz + a1.w);
                vo[bi][vi][2] += w * (a2.x*ux + a2.y*uy + a2.z*uz + a2.w);
            }
        }
    }
#pragma unroll
    for (int bi = 0; bi < 2; bi++)
#pragma unroll
        for (int vi = 0; vi < 4; vi++) {
            const int v = v0 + vi*16 + vg;
            if (v < VV) {
                const size_t base = (size_t)(b0 + bg*2 + bi)*N3 + (size_t)v*3;
#pragma unroll
                for (int k = 0; k < 3; k++) out[base+k] = vo[bi][vi][k];
            }
        }
}

// ---- K4: extra9 + h36m17 regressors + 11 gathered joints ----
__global__ __launch_bounds__(256) void k_joints(
    const float* __restrict__ Je9, const float* __restrict__ Jh,
    const int* __restrict__ eidx, float* __restrict__ out)
{
    const int b = blockIdx.x;
    const int wv = threadIdx.x >> 6, ln = threadIdx.x & 63;
    const int j0 = (wv == 0) ? 0 : (wv == 1) ? 7 : (wv == 2) ? 14 : 20;
    const int jn = (wv < 2) ? 7 : 6;
    float acc[7][3];
#pragma unroll
    for (int t = 0; t < 7; t++)
#pragma unroll
        for (int k = 0; k < 3; k++) acc[t][k] = 0.f;
    const float* vb = out + (size_t)b*VV*3;
    for (int v = ln; v < VV; v += 64) {
        const float x = vb[v*3+0], y = vb[v*3+1], z = vb[v*3+2];
#pragma unroll
        for (int t = 0; t < 7; t++) {
            if (t < jn) {
                const int jj = j0 + t;
                const float jr = (jj < 9) ? Je9[(size_t)jj*VV + v] : Jh[(size_t)(jj-9)*VV + v];
                acc[t][0] += jr*x; acc[t][1] += jr*y; acc[t][2] += jr*z;
            }
        }
    }
#pragma unroll
    for (int off = 1; off < 64; off <<= 1)
#pragma unroll
        for (int t = 0; t < 7; t++)
#pragma unroll
            for (int k = 0; k < 3; k++) acc[t][k] += __shfl_xor(acc[t][k], off);
    if (ln == 0)
#pragma unroll
        for (int t = 0; t < 7; t++)
            if (t < jn)
#pragma unroll
                for (int k = 0; k < 3; k++)
                    out[OUTJ + ((size_t)b*NJOUT + 35 + j0 + t)*3 + k] = acc[t][k];
    if (wv == 0 && ln < 33) {
        const int j = ln / 3, k = ln % 3;
        out[OUTJ + ((size_t)b*NJOUT + 24 + j)*3 + k] = vb[(size_t)eidx[j]*3 + k];
    }
}

extern "C" void kernel_launch(void* const* d_in, const int* in_sizes, int n_in,
                              void* d_out, int out_size, void* d_ws, size_t ws_size,
                              hipStream_t stream) {
    const float* betas = (const float*)d_in[0];
    const float* poses = (const float*)d_in[1];
    const int*   eidx  = (const int*)  d_in[2];
    const float* vt    = (const float*)d_in[3];
    const float* sd    = (const float*)d_in[4];
    const float* pd    = (const float*)d_in[5];
    const float* Jreg  = (const float*)d_in[6];
    const float* lbsw  = (const float*)d_in[7];
    const float* Je9   = (const float*)d_in[8];
    const float* Jh    = (const float*)d_in[9];
    float* out = (float*)d_out;
    float* ws  = (float*)d_ws;
    short* Ablk = (short*)((char*)d_ws + WS_ABLK_BYTES);
    short* Bblk = (short*)((char*)d_ws + WS_BBLK_BYTES);

    k_buildB  <<<dim3(NT, NKC), dim3(256), 0, stream>>>(pd, sd, Bblk);
    k_jointreg<<<dim3(72),      dim3(256), 0, stream>>>(Jreg, vt, sd, ws);
    k_batch   <<<dim3(1024),    dim3(64),  0, stream>>>(betas, poses, ws, Ablk, out);
    k_gemm    <<<dim3(NT, 8),   dim3(256), 0, stream>>>(Ablk, Bblk, vt, out);
    k_lbs     <<<dim3(108, 32), dim3(256), 0, stream>>>(ws + WS_A, lbsw, out);
    k_joints  <<<dim3(1024),    dim3(256), 0, stream>>>(Je9, Jh, eidx, out);
}

// Round 3
// 192.264 us; speedup vs baseline: 7.5932x; 7.5932x over previous
//
#include <hip/hip_runtime.h>

#define VV 6890
#define N3 20670      // V*3
#define NVT 216       // ceil(N3/96) vertex tiles (32 verts each)
#define NKC 7         // K chunks of 32 (K=224)
#define NJOUT 61
#define OUTJ ((size_t)1024*VV*3)

// ws layout: floats JT[72]@0, JS[720]@72, A(rel transforms f32 1024*288)@1024;
// bytes: Ablk bf16 @1183744 (448KB), Bblk bf16 @1642496 (9.29MB)
#define WS_JT 0
#define WS_JS 72
#define WS_A  1024
#define WS_ABLK_BYTES 1183744
#define WS_BBLK_BYTES 1642496

typedef float f32x4 __attribute__((ext_vector_type(4)));
typedef short bf16x8 __attribute__((ext_vector_type(8)));

__constant__ int c_par[24] = {-1,0,0,0,1,2,3,4,5,6,7,8,9,9,9,12,13,14,16,17,18,19,20,21};

__device__ __forceinline__ short f2bf(float x) {
    union { float f; unsigned u; } v; v.f = x;
    unsigned r = (v.u + 0x7fffu + ((v.u >> 16) & 1u)) >> 16;
    return (short)r;
}

// ---- K0a: build tiled/transposed/swizzled bf16 B matrix, 96-col tiles ----
// logical B[k][n]: k<207 -> posedirs[k][n]; 207<=k<217 -> shapedirs[n/3][n%3][k-207]; else 0
// tile [nt][kc]: 96 cols x 32 k bf16 (6144B); col c 64B row, k-group hi at slot (hi^((c>>1)&3))
__global__ __launch_bounds__(256) void k_buildB(
    const float* __restrict__ pd, const float* __restrict__ sd, short* __restrict__ Bblk)
{
    const int nt = blockIdx.x, kc = blockIdx.y;
    const int tid = threadIdx.x;
    __shared__ float T[32][97];
    for (int idx = tid; idx < 3072; idx += 256) {
        const int kl = idx / 96, c = idx % 96;
        const int kg = kc*32 + kl;
        const int n = nt*96 + c;
        float val = 0.f;
        if (n < N3) {
            if (kg < 207) val = pd[(size_t)kg*N3 + n];
            else if (kg < 217) val = sd[(size_t)(n/3)*30 + (n%3)*10 + (kg-207)];
        }
        T[kl][c] = val;
    }
    __syncthreads();
    short* tile = Bblk + (size_t)(nt*NKC + kc)*3072;
    for (int s = tid; s < 384; s += 256) {
        const int c = s >> 2;
        const int hi = (s & 3) ^ ((c >> 1) & 3);
        bf16x8 pk;
#pragma unroll
        for (int e = 0; e < 8; e++) pk[e] = f2bf(T[hi*8+e][c]);
        *(bf16x8*)(tile + s*8) = pk;
    }
}

// ---- K0b: JT = Jreg@v_template, JS = Jreg@shapedirs (exact f32) ----
__global__ __launch_bounds__(256) void k_jointreg(
    const float* __restrict__ Jreg, const float* __restrict__ vt,
    const float* __restrict__ sd, float* __restrict__ ws)
{
    const int j = blockIdx.x / 3, k = blockIdx.x % 3;
    float acc[11];
#pragma unroll
    for (int i = 0; i < 11; i++) acc[i] = 0.f;
    for (int v = threadIdx.x; v < VV; v += 256) {
        const float jr = Jreg[j*VV + v];
        acc[0] += jr * vt[v*3 + k];
        const float* s = sd + (size_t)v*30 + k*10;
#pragma unroll
        for (int l = 0; l < 10; l++) acc[1+l] += jr * s[l];
    }
#pragma unroll
    for (int off = 1; off < 64; off <<= 1)
#pragma unroll
        for (int i = 0; i < 11; i++) acc[i] += __shfl_xor(acc[i], off);
    __shared__ float red[4][11];
    const int wv = threadIdx.x >> 6, ln = threadIdx.x & 63;
    if (ln == 0)
#pragma unroll
        for (int i = 0; i < 11; i++) red[wv][i] = acc[i];
    __syncthreads();
    if (threadIdx.x == 0) {
        ws[WS_JT + j*3 + k] = red[0][0]+red[1][0]+red[2][0]+red[3][0];
#pragma unroll
        for (int l = 0; l < 10; l++)
            ws[WS_JS + (j*3+k)*10 + l] = red[0][1+l]+red[1][1+l]+red[2][1+l]+red[3][1+l];
    }
}

// ---- K1: rodrigues + chain + rel transforms (f32) + bf16 A-matrix (32-row tiles) + joints[0:24] ----
__global__ __launch_bounds__(64) void k_batch(
    const float* __restrict__ betas, const float* __restrict__ poses,
    float* __restrict__ ws, short* __restrict__ Ablk, float* __restrict__ out)
{
    const int b = blockIdx.x, lane = threadIdx.x;
    __shared__ float R[24][9], Jr[24][3], RJ[24][3], G[24][12];
    if (lane < 24) {
        const int j = lane;
        const float x = poses[b*72 + j*3 + 0];
        const float y = poses[b*72 + j*3 + 1];
        const float z = poses[b*72 + j*3 + 2];
        const float xe = x + 1e-8f, ye = y + 1e-8f, ze = z + 1e-8f;
        const float ang = sqrtf(xe*xe + ye*ye + ze*ze);
        const float inv = 1.0f / ang;
        const float rx = x*inv, ry = y*inv, rz = z*inv;
        const float sn = sinf(ang), cs = cosf(ang);
        const float K[9] = {0.f,-rz,ry, rz,0.f,-rx, -ry,rx,0.f};
        float Rl[9];
#pragma unroll
        for (int r = 0; r < 3; r++)
#pragma unroll
            for (int c = 0; c < 3; c++) {
                float kk = 0.f;
#pragma unroll
                for (int m = 0; m < 3; m++) kk += K[r*3+m]*K[m*3+c];
                Rl[r*3+c] = ((r==c)?1.f:0.f) + sn*K[r*3+c] + (1.f-cs)*kk;
            }
#pragma unroll
        for (int e = 0; e < 9; e++) R[j][e] = Rl[e];
#pragma unroll
        for (int k = 0; k < 3; k++) {
            float a = ws[WS_JT + j*3 + k];
#pragma unroll
            for (int l = 0; l < 10; l++) a += betas[b*10 + l] * ws[WS_JS + (j*3+k)*10 + l];
            Jr[j][k] = a;
        }
    }
    __syncthreads();
    // bf16 A-matrix row (224 wide): [pose_feature(207) | betas(10) | zeros], 32-row tiles
    {
        const int r = b & 31, mt = b >> 5;
        const int sw = (r >> 1) & 3;
        for (int k = lane; k < 224; k += 64) {
            float val;
            if (k < 207) { const int j = k/9 + 1, e = k - (j-1)*9;
                           val = R[j][e] - ((e==0||e==4||e==8)?1.f:0.f); }
            else if (k < 217) val = betas[b*10 + (k-207)];
            else val = 0.f;
            const int kc = k >> 5, hi = (k >> 3) & 3;
            Ablk[(size_t)(mt*NKC + kc)*1024 + r*32 + ((hi ^ sw)*8) + (k & 7)] = f2bf(val);
        }
    }
    if (lane < 24) {
        const int j = lane, p = c_par[j];
#pragma unroll
        for (int k = 0; k < 3; k++) RJ[j][k] = (j == 0) ? Jr[0][k] : (Jr[j][k] - Jr[p][k]);
    }
    __syncthreads();
    if (lane < 12) {
        const int r = lane >> 2, c = lane & 3;
        G[0][lane] = (c < 3) ? R[0][r*3+c] : RJ[0][r];
    }
    __syncthreads();
    for (int i = 1; i < 24; i++) {
        float val = 0.f;
        if (lane < 12) {
            const int r = lane >> 2, c = lane & 3, p = c_par[i];
            if (c < 3)
                val = G[p][r*4+0]*R[i][0+c] + G[p][r*4+1]*R[i][3+c] + G[p][r*4+2]*R[i][6+c];
            else
                val = G[p][r*4+0]*RJ[i][0] + G[p][r*4+1]*RJ[i][1] + G[p][r*4+2]*RJ[i][2] + G[p][r*4+3];
        }
        __syncthreads();
        if (lane < 12) G[i][lane] = val;
        __syncthreads();
    }
    if (lane < 24)
#pragma unroll
        for (int k = 0; k < 3; k++)
            out[OUTJ + ((size_t)b*NJOUT + lane)*3 + k] = G[lane][k*4+3];
    for (int e = lane; e < 288; e += 64) {
        const int j = e / 12, rc = e % 12, r = rc >> 2, c = rc & 3;
        float val = G[j][rc];
        if (c == 3)
            val -= G[j][r*4+0]*Jr[j][0] + G[j][r*4+1]*Jr[j][1] + G[j][r*4+2]*Jr[j][2];
        ws[WS_A + (size_t)b*288 + e] = val;
    }
}

// ---- K2: FUSED bf16 MFMA GEMM + LBS. Block = 32 batches x 96 cols (32 verts). ----
// Phase1: v_posed GEMM via MFMA; Phase2: acc+vt -> LDS vp[32][32][4]; Phase3: LBS -> out.
__global__ __launch_bounds__(256) void k_fused(
    const short* __restrict__ Ablk, const short* __restrict__ Bblk,
    const float* __restrict__ vt, const float* __restrict__ Ag,
    const float* __restrict__ lbsw, float* __restrict__ out)
{
    const int nt = blockIdx.x, bt = blockIdx.y;
    const int tid = threadIdx.x;
    const int lane = tid & 63, wid = tid >> 6;
    const int wm = wid >> 1, wn = wid & 1;

    __shared__ char SM[27776] __attribute__((aligned(16)));
    float4* SM4 = (float4*)SM;            // staging: A [0..127], B [128..511] (8KB)
    short*  SMs = (short*)SM;
    float*  vp  = (float*)(SM + 8192);    // [32 b][32 v][4] = 16KB
    float*  Ws  = (float*)(SM + 24576);   // [32 v][25] = 3.2KB

    // stage lbs weights for this vertex tile
    for (int i = tid; i < 768; i += 256) {
        const int r = i / 24, c = i % 24;
        const int v = nt*32 + r;
        Ws[r*25 + c] = (v < VV) ? lbsw[(size_t)v*24 + c] : 0.f;
    }

    f32x4 acc[3];
#pragma unroll
    for (int n = 0; n < 3; n++) acc[n] = (f32x4){0.f,0.f,0.f,0.f};

    const int hi = lane >> 4;
    const int ar = wm*16 + (lane & 15);
    const int aoff = ar*32 + ((hi ^ ((ar >> 1) & 3)) * 8);
    int boff[3];
#pragma unroll
    for (int n = 0; n < 3; n++) {
        const int c = wn*48 + n*16 + (lane & 15);
        boff[n] = 1024 + c*32 + ((hi ^ ((c >> 1) & 3)) * 8);
    }
    const float4* gA4 = (const float4*)Ablk + (size_t)bt*NKC*128;
    const float4* gB4 = (const float4*)Bblk + (size_t)nt*NKC*384;

    for (int kc = 0; kc < NKC; kc++) {
        __syncthreads();
        SM4[tid]       = (tid < 128) ? gA4[kc*128 + tid] : gB4[kc*384 + tid - 128];
        SM4[tid + 256] = gB4[kc*384 + tid + 128];
        __syncthreads();
        const bf16x8 af = *(const bf16x8*)&SMs[aoff];
#pragma unroll
        for (int n = 0; n < 3; n++) {
            const bf16x8 bf = *(const bf16x8*)&SMs[boff[n]];
            acc[n] = __builtin_amdgcn_mfma_f32_16x16x32_bf16(af, bf, acc[n], 0, 0, 0);
        }
    }
    // phase 2: acc + v_template -> vp LDS
#pragma unroll
    for (int n = 0; n < 3; n++) {
        const int cl = wn*48 + n*16 + (lane & 15);
        const int cg = nt*96 + cl;
        const float vtv = (cg < N3) ? vt[cg] : 0.f;
        const int vloc = cl / 3, kk = cl - vloc*3;
        const int b0 = wm*16 + hi*4;
#pragma unroll
        for (int rg = 0; rg < 4; rg++)
            vp[(b0+rg)*128 + vloc*4 + kk] = acc[n][rg] + vtv;
    }
    __syncthreads();

    // phase 3: LBS. thread -> 1 batch (tid>>3), 4 verts (tid&7 + 8i)
    const int bl = tid >> 3, vq = tid & 7;
    const int bg = bt*32 + bl;
    float4 u[4];
#pragma unroll
    for (int i = 0; i < 4; i++) u[i] = *(const float4*)&vp[bl*128 + (vq + 8*i)*4];
    float ac[4][3];
#pragma unroll
    for (int i = 0; i < 4; i++)
#pragma unroll
        for (int k = 0; k < 3; k++) ac[i][k] = 0.f;
    const float* arow = Ag + (size_t)bg*288;
#pragma unroll 2
    for (int j = 0; j < 24; j++) {
        const float4 a0 = *(const float4*)(arow + j*12);
        const float4 a1 = *(const float4*)(arow + j*12 + 4);
        const float4 a2 = *(const float4*)(arow + j*12 + 8);
#pragma unroll
        for (int i = 0; i < 4; i++) {
            const float w = Ws[(vq + 8*i)*25 + j];
            ac[i][0] += w * (a0.x*u[i].x + a0.y*u[i].y + a0.z*u[i].z + a0.w);
            ac[i][1] += w * (a1.x*u[i].x + a1.y*u[i].y + a1.z*u[i].z + a1.w);
            ac[i][2] += w * (a2.x*u[i].x + a2.y*u[i].y + a2.z*u[i].z + a2.w);
        }
    }
#pragma unroll
    for (int i = 0; i < 4; i++) {
        const int v = nt*32 + vq + 8*i;
        if (v < VV) {
            const size_t base = (size_t)bg*N3 + (size_t)v*3;
            out[base+0] = ac[i][0];
            out[base+1] = ac[i][1];
            out[base+2] = ac[i][2];
        }
    }
}

// ---- K3: extra9 + h36m17 regressors + 11 gathered joints ----
__global__ __launch_bounds__(256) void k_joints(
    const float* __restrict__ Je9, const float* __restrict__ Jh,
    const int* __restrict__ eidx, float* __restrict__ out)
{
    const int b = blockIdx.x;
    const int wv = threadIdx.x >> 6, ln = threadIdx.x & 63;
    const int j0 = (wv == 0) ? 0 : (wv == 1) ? 7 : (wv == 2) ? 14 : 20;
    const int jn = (wv < 2) ? 7 : 6;
    float acc[7][3];
#pragma unroll
    for (int t = 0; t < 7; t++)
#pragma unroll
        for (int k = 0; k < 3; k++) acc[t][k] = 0.f;
    const float* vb = out + (size_t)b*VV*3;
    for (int v = ln; v < VV; v += 64) {
        const float x = vb[v*3+0], y = vb[v*3+1], z = vb[v*3+2];
#pragma unroll
        for (int t = 0; t < 7; t++) {
            if (t < jn) {
                const int jj = j0 + t;
                const float jr = (jj < 9) ? Je9[(size_t)jj*VV + v] : Jh[(size_t)(jj-9)*VV + v];
                acc[t][0] += jr*x; acc[t][1] += jr*y; acc[t][2] += jr*z;
            }
        }
    }
#pragma unroll
    for (int off = 1; off < 64; off <<= 1)
#pragma unroll
        for (int t = 0; t < 7; t++)
#pragma unroll
            for (int k = 0; k < 3; k++) acc[t][k] += __shfl_xor(acc[t][k], off);
    if (ln == 0)
#pragma unroll
        for (int t = 0; t < 7; t++)
            if (t < jn)
#pragma unroll
                for (int k = 0; k < 3; k++)
                    out[OUTJ + ((size_t)b*NJOUT + 35 + j0 + t)*3 + k] = acc[t][k];
    if (wv == 0 && ln < 33) {
        const int j = ln / 3, k = ln % 3;
        out[OUTJ + ((size_t)b*NJOUT + 24 + j)*3 + k] = vb[(size_t)eidx[j]*3 + k];
    }
}

extern "C" void kernel_launch(void* const* d_in, const int* in_sizes, int n_in,
                              void* d_out, int out_size, void* d_ws, size_t ws_size,
                              hipStream_t stream) {
    const float* betas = (const float*)d_in[0];
    const float* poses = (const float*)d_in[1];
    const int*   eidx  = (const int*)  d_in[2];
    const float* vt    = (const float*)d_in[3];
    const float* sd    = (const float*)d_in[4];
    const float* pd    = (const float*)d_in[5];
    const float* Jreg  = (const float*)d_in[6];
    const float* lbsw  = (const float*)d_in[7];
    const float* Je9   = (const float*)d_in[8];
    const float* Jh    = (const float*)d_in[9];
    float* out = (float*)d_out;
    float* ws  = (float*)d_ws;
    short* Ablk = (short*)((char*)d_ws + WS_ABLK_BYTES);
    short* Bblk = (short*)((char*)d_ws + WS_BBLK_BYTES);

    k_buildB  <<<dim3(NVT, NKC), dim3(256), 0, stream>>>(pd, sd, Bblk);
    k_jointreg<<<dim3(72),       dim3(256), 0, stream>>>(Jreg, vt, sd, ws);
    k_batch   <<<dim3(1024),     dim3(64),  0, stream>>>(betas, poses, ws, Ablk, out);
    k_fused   <<<dim3(NVT, 32),  dim3(256), 0, stream>>>(Ablk, Bblk, vt, ws + WS_A, lbsw, out);
    k_joints  <<<dim3(1024),     dim3(256), 0, stream>>>(Je9, Jh, eidx, out);
}

// Round 4
// 181.774 us; speedup vs baseline: 8.0314x; 1.0577x over previous
//
#include <hip/hip_runtime.h>

#define VV 6890
#define N3 20670      // V*3
#define NVT 216       // ceil(N3/96) vertex tiles (32 verts each)
#define NKC 7         // K chunks of 32 (K=224)
#define NJOUT 61
#define OUTJ ((size_t)1024*VV*3)

// ws layout: floats JT[72]@0, JS[720]@72, A(rel transforms f32 1024*288)@1024;
// bytes: Ablk bf16 @1183744 (448KB), Bblk bf16 @1642496 (9.29MB),
//        A2 frags @10932224 (1.5MB), W2 frags @12505088 (432KB) -> end 12947456
#define WS_JT 0
#define WS_JS 72
#define WS_A  1024
#define WS_ABLK_BYTES 1183744
#define WS_BBLK_BYTES 1642496
#define WS_A2_BYTES   10932224
#define WS_W2_BYTES   12505088

typedef float f32x4 __attribute__((ext_vector_type(4)));
typedef short bf16x8 __attribute__((ext_vector_type(8)));

__constant__ int c_par[24] = {-1,0,0,0,1,2,3,4,5,6,7,8,9,9,9,12,13,14,16,17,18,19,20,21};

__device__ __forceinline__ short f2bf(float x) {
    union { float f; unsigned u; } v; v.f = x;
    unsigned r = (v.u + 0x7fffu + ((v.u >> 16) & 1u)) >> 16;
    return (short)r;
}
__device__ __forceinline__ float bf2f(short h) {
    union { unsigned u; float f; } v; v.u = ((unsigned)(unsigned short)h) << 16;
    return v.f;
}

// ---- K0a: build tiled/transposed/swizzled bf16 B matrix, 96-col tiles ----
__global__ __launch_bounds__(256) void k_buildB(
    const float* __restrict__ pd, const float* __restrict__ sd, short* __restrict__ Bblk)
{
    const int nt = blockIdx.x, kc = blockIdx.y;
    const int tid = threadIdx.x;
    __shared__ float T[32][97];
    for (int idx = tid; idx < 3072; idx += 256) {
        const int kl = idx / 96, c = idx % 96;
        const int kg = kc*32 + kl;
        const int n = nt*96 + c;
        float val = 0.f;
        if (n < N3) {
            if (kg < 207) val = pd[(size_t)kg*N3 + n];
            else if (kg < 217) val = sd[(size_t)(n/3)*30 + (n%3)*10 + (kg-207)];
        }
        T[kl][c] = val;
    }
    __syncthreads();
    short* tile = Bblk + (size_t)(nt*NKC + kc)*3072;
    for (int s = tid; s < 384; s += 256) {
        const int c = s >> 2;
        const int hi = (s & 3) ^ ((c >> 1) & 3);
        bf16x8 pk;
#pragma unroll
        for (int e = 0; e < 8; e++) pk[e] = f2bf(T[hi*8+e][c]);
        *(bf16x8*)(tile + s*8) = pk;
    }
}

// ---- K0w: build W2 fragments: per nt, per nh: lane l holds w[v=nh*16+(l&15), j=(l>>4)*8+q] ----
__global__ __launch_bounds__(64) void k_buildW(
    const float* __restrict__ lbsw, short* __restrict__ W2)
{
    const int nt = blockIdx.x, l = threadIdx.x;
    const int l15 = l & 15, l4 = l >> 4;
#pragma unroll
    for (int nh = 0; nh < 2; nh++) {
        const int v = nt*32 + nh*16 + l15;
        bf16x8 pk;
#pragma unroll
        for (int q = 0; q < 8; q++) {
            const int j = l4*8 + q;
            float val = (j < 24 && v < VV) ? lbsw[(size_t)v*24 + j] : 0.f;
            pk[q] = f2bf(val);
        }
        *(bf16x8*)(W2 + ((size_t)(nt*2 + nh)*512) + l*8) = pk;
    }
}

// ---- K0b: JT = Jreg@v_template, JS = Jreg@shapedirs (exact f32) ----
__global__ __launch_bounds__(256) void k_jointreg(
    const float* __restrict__ Jreg, const float* __restrict__ vt,
    const float* __restrict__ sd, float* __restrict__ ws)
{
    const int j = blockIdx.x / 3, k = blockIdx.x % 3;
    float acc[11];
#pragma unroll
    for (int i = 0; i < 11; i++) acc[i] = 0.f;
    for (int v = threadIdx.x; v < VV; v += 256) {
        const float jr = Jreg[j*VV + v];
        acc[0] += jr * vt[v*3 + k];
        const float* s = sd + (size_t)v*30 + k*10;
#pragma unroll
        for (int l = 0; l < 10; l++) acc[1+l] += jr * s[l];
    }
#pragma unroll
    for (int off = 1; off < 64; off <<= 1)
#pragma unroll
        for (int i = 0; i < 11; i++) acc[i] += __shfl_xor(acc[i], off);
    __shared__ float red[4][11];
    const int wv = threadIdx.x >> 6, ln = threadIdx.x & 63;
    if (ln == 0)
#pragma unroll
        for (int i = 0; i < 11; i++) red[wv][i] = acc[i];
    __syncthreads();
    if (threadIdx.x == 0) {
        ws[WS_JT + j*3 + k] = red[0][0]+red[1][0]+red[2][0]+red[3][0];
#pragma unroll
        for (int l = 0; l < 10; l++)
            ws[WS_JS + (j*3+k)*10 + l] = red[0][1+l]+red[1][1+l]+red[2][1+l]+red[3][1+l];
    }
}

// ---- K1: rodrigues + chain + bf16 A-matrix + A2 hi/lo fragments + joints[0:24] ----
__global__ __launch_bounds__(64) void k_batch(
    const float* __restrict__ betas, const float* __restrict__ poses,
    float* __restrict__ ws, short* __restrict__ Ablk, short* __restrict__ A2,
    float* __restrict__ out)
{
    const int b = blockIdx.x, lane = threadIdx.x;
    __shared__ float R[24][9], Jr[24][3], RJ[24][3], G[24][12];
    if (lane < 24) {
        const int j = lane;
        const float x = poses[b*72 + j*3 + 0];
        const float y = poses[b*72 + j*3 + 1];
        const float z = poses[b*72 + j*3 + 2];
        const float xe = x + 1e-8f, ye = y + 1e-8f, ze = z + 1e-8f;
        const float ang = sqrtf(xe*xe + ye*ye + ze*ze);
        const float inv = 1.0f / ang;
        const float rx = x*inv, ry = y*inv, rz = z*inv;
        const float sn = sinf(ang), cs = cosf(ang);
        const float K[9] = {0.f,-rz,ry, rz,0.f,-rx, -ry,rx,0.f};
        float Rl[9];
#pragma unroll
        for (int r = 0; r < 3; r++)
#pragma unroll
            for (int c = 0; c < 3; c++) {
                float kk = 0.f;
#pragma unroll
                for (int m = 0; m < 3; m++) kk += K[r*3+m]*K[m*3+c];
                Rl[r*3+c] = ((r==c)?1.f:0.f) + sn*K[r*3+c] + (1.f-cs)*kk;
            }
#pragma unroll
        for (int e = 0; e < 9; e++) R[j][e] = Rl[e];
#pragma unroll
        for (int k = 0; k < 3; k++) {
            float a = ws[WS_JT + j*3 + k];
#pragma unroll
            for (int l = 0; l < 10; l++) a += betas[b*10 + l] * ws[WS_JS + (j*3+k)*10 + l];
            Jr[j][k] = a;
        }
    }
    __syncthreads();
    // bf16 A-matrix row (224 wide): [pose_feature(207) | betas(10) | zeros], 32-row tiles
    {
        const int r = b & 31, mt = b >> 5;
        const int sw = (r >> 1) & 3;
        for (int k = lane; k < 224; k += 64) {
            float val;
            if (k < 207) { const int j = k/9 + 1, e = k - (j-1)*9;
                           val = R[j][e] - ((e==0||e==4||e==8)?1.f:0.f); }
            else if (k < 217) val = betas[b*10 + (k-207)];
            else val = 0.f;
            const int kc = k >> 5, hi = (k >> 3) & 3;
            Ablk[(size_t)(mt*NKC + kc)*1024 + r*32 + ((hi ^ sw)*8) + (k & 7)] = f2bf(val);
        }
    }
    if (lane < 24) {
        const int j = lane, p = c_par[j];
#pragma unroll
        for (int k = 0; k < 3; k++) RJ[j][k] = (j == 0) ? Jr[0][k] : (Jr[j][k] - Jr[p][k]);
    }
    __syncthreads();
    if (lane < 12) {
        const int r = lane >> 2, c = lane & 3;
        G[0][lane] = (c < 3) ? R[0][r*3+c] : RJ[0][r];
    }
    __syncthreads();
    for (int i = 1; i < 24; i++) {
        float val = 0.f;
        if (lane < 12) {
            const int r = lane >> 2, c = lane & 3, p = c_par[i];
            if (c < 3)
                val = G[p][r*4+0]*R[i][0+c] + G[p][r*4+1]*R[i][3+c] + G[p][r*4+2]*R[i][6+c];
            else
                val = G[p][r*4+0]*RJ[i][0] + G[p][r*4+1]*RJ[i][1] + G[p][r*4+2]*RJ[i][2] + G[p][r*4+3];
        }
        __syncthreads();
        if (lane < 12) G[i][lane] = val;
        __syncthreads();
    }
    if (lane < 24)
#pragma unroll
        for (int k = 0; k < 3; k++)
            out[OUTJ + ((size_t)b*NJOUT + lane)*3 + k] = G[lane][k*4+3];
    // rel transforms -> A2 hi/lo fragments (pre-swizzled for 16x16x32 MFMA A-operand)
    const int bt = b >> 5, mh = (b >> 4) & 1, b15 = b & 15;
    short* A2t = A2 + (size_t)bt*12*2*2*512;
    for (int e = lane; e < 288; e += 64) {
        const int j = e / 12, rc = e % 12, r = rc >> 2, c = rc & 3;
        float val = G[j][rc];
        if (c == 3)
            val -= G[j][r*4+0]*Jr[j][0] + G[j][r*4+1]*Jr[j][1] + G[j][r*4+2]*Jr[j][2];
        const short vhi = f2bf(val);
        const short vlo = f2bf(val - bf2f(vhi));
        const int lf = (j >> 3)*16 + b15, q = j & 7;
        A2t[((rc*2 + 0)*2 + mh)*512 + lf*8 + q] = vhi;
        A2t[((rc*2 + 1)*2 + mh)*512 + lf*8 + q] = vlo;
    }
    // zero-pad j=24..31 in fragments
    for (int idx = lane; idx < 192; idx += 64) {
        const int rc = idx >> 4, spl = (idx >> 3) & 1, q = idx & 7;
        A2t[((rc*2 + spl)*2 + mh)*512 + (48 + b15)*8 + q] = 0;
    }
}

// ---- K2: FUSED. Phase1: pose GEMM (MFMA). Phase2: vp->LDS. Phase3: T = w*A (MFMA). Phase4: verts. ----
__global__ __launch_bounds__(256) void k_fused(
    const short* __restrict__ Ablk, const short* __restrict__ Bblk,
    const short* __restrict__ A2, const short* __restrict__ W2,
    const float* __restrict__ vt, float* __restrict__ out)
{
    const int nt = blockIdx.x, bt = blockIdx.y;
    const int tid = threadIdx.x;
    const int lane = tid & 63, wid = tid >> 6;
    const int wm = wid >> 1, wn = wid & 1;
    const int l15 = lane & 15, l4 = lane >> 4;

    __shared__ char SM[66560] __attribute__((aligned(16)));
    float*  vp  = (float*)SM;             // [32 b][132] (vert*4 + pad) = 16896 B
    float*  Tl  = (float*)(SM + 16896);   // [32 b][388] (32v*12 + pad) = 49664 B
    float4* SG4 = (float4*)(SM + 16896);  // staging overlaps T (phases disjoint)
    short*  SGs = (short*)(SM + 16896);

    // ---- early issue: phase-3 operand fragments (hidden under phase 1) ----
    const int e_base = wid*3;
    bf16x8 a2f[3][2][2], w2f[2];
    {
        const short* A2t = A2 + (size_t)bt*12*2*2*512;
#pragma unroll
        for (int ee = 0; ee < 3; ee++)
#pragma unroll
            for (int mh = 0; mh < 2; mh++)
#pragma unroll
                for (int spl = 0; spl < 2; spl++)
                    a2f[ee][mh][spl] = *(const bf16x8*)(A2t + (((e_base+ee)*2 + spl)*2 + mh)*512 + lane*8);
#pragma unroll
        for (int nh = 0; nh < 2; nh++)
            w2f[nh] = *(const bf16x8*)(W2 + (size_t)(nt*2 + nh)*512 + lane*8);
    }

    // ---- phase 1: pose GEMM ----
    f32x4 acc[3];
#pragma unroll
    for (int n = 0; n < 3; n++) acc[n] = (f32x4){0.f,0.f,0.f,0.f};
    const int ar = wm*16 + l15;
    const int aoff = ar*32 + ((l4 ^ ((ar >> 1) & 3)) * 8);
    int boff[3];
#pragma unroll
    for (int n = 0; n < 3; n++) {
        const int c = wn*48 + n*16 + l15;
        boff[n] = 1024 + c*32 + ((l4 ^ ((c >> 1) & 3)) * 8);
    }
    const float4* gA4 = (const float4*)Ablk + (size_t)bt*NKC*128;
    const float4* gB4 = (const float4*)Bblk + (size_t)nt*NKC*384;

    for (int kc = 0; kc < NKC; kc++) {
        __syncthreads();
        SG4[tid]       = (tid < 128) ? gA4[kc*128 + tid] : gB4[kc*384 + tid - 128];
        SG4[tid + 256] = gB4[kc*384 + tid + 128];
        __syncthreads();
        const bf16x8 af = *(const bf16x8*)&SGs[aoff];
#pragma unroll
        for (int n = 0; n < 3; n++) {
            const bf16x8 bf = *(const bf16x8*)&SGs[boff[n]];
            acc[n] = __builtin_amdgcn_mfma_f32_16x16x32_bf16(af, bf, acc[n], 0, 0, 0);
        }
    }
    // ---- phase 2: acc + v_template -> vp ----
#pragma unroll
    for (int n = 0; n < 3; n++) {
        const int cl = wn*48 + n*16 + l15;
        const int cg = nt*96 + cl;
        const float vtv = (cg < N3) ? vt[cg] : 0.f;
        const int vloc = cl / 3, kk = cl - vloc*3;
        const int b0 = wm*16 + l4*4;
#pragma unroll
        for (int rg = 0; rg < 4; rg++)
            vp[(b0+rg)*132 + vloc*4 + kk] = acc[n][rg] + vtv;
    }
    __syncthreads();   // staging reads done everywhere; T region now writable

    // ---- phase 3: T-tile via MFMA: T_e[b,v] = sum_j A_e[b,j] * w[v,j] ----
#pragma unroll
    for (int ee = 0; ee < 3; ee++) {
        const int e = e_base + ee;
#pragma unroll
        for (int mh = 0; mh < 2; mh++)
#pragma unroll
            for (int nh = 0; nh < 2; nh++) {
                f32x4 at = (f32x4){0.f,0.f,0.f,0.f};
                at = __builtin_amdgcn_mfma_f32_16x16x32_bf16(a2f[ee][mh][0], w2f[nh], at, 0, 0, 0);
                at = __builtin_amdgcn_mfma_f32_16x16x32_bf16(a2f[ee][mh][1], w2f[nh], at, 0, 0, 0);
                const int brow = mh*16 + l4*4, vcol = nh*16 + l15;
#pragma unroll
                for (int rg = 0; rg < 4; rg++)
                    Tl[(brow+rg)*388 + vcol*12 + e] = at[rg];
            }
    }
    __syncthreads();

    // ---- phase 4: verts = T * [u,1] ----
    const int bl = tid >> 3, vq = tid & 7;
    const int bg = bt*32 + bl;
#pragma unroll
    for (int i = 0; i < 4; i++) {
        const int v = vq + 8*i;
        const float4 u  = *(const float4*)&vp[bl*132 + v*4];
        const float4 t0 = *(const float4*)&Tl[bl*388 + v*12 + 0];
        const float4 t1 = *(const float4*)&Tl[bl*388 + v*12 + 4];
        const float4 t2 = *(const float4*)&Tl[bl*388 + v*12 + 8];
        const float r0 = t0.x*u.x + t0.y*u.y + t0.z*u.z + t0.w;
        const float r1 = t1.x*u.x + t1.y*u.y + t1.z*u.z + t1.w;
        const float r2 = t2.x*u.x + t2.y*u.y + t2.z*u.z + t2.w;
        const int gv = nt*32 + v;
        if (gv < VV) {
            const size_t base = (size_t)bg*N3 + (size_t)gv*3;
            out[base+0] = r0; out[base+1] = r1; out[base+2] = r2;
        }
    }
}

// ---- K3: extra9 + h36m17 regressors + 11 gathered joints ----
__global__ __launch_bounds__(256) void k_joints(
    const float* __restrict__ Je9, const float* __restrict__ Jh,
    const int* __restrict__ eidx, float* __restrict__ out)
{
    const int b = blockIdx.x;
    const int wv = threadIdx.x >> 6, ln = threadIdx.x & 63;
    const int j0 = (wv == 0) ? 0 : (wv == 1) ? 7 : (wv == 2) ? 14 : 20;
    const int jn = (wv < 2) ? 7 : 6;
    float acc[7][3];
#pragma unroll
    for (int t = 0; t < 7; t++)
#pragma unroll
        for (int k = 0; k < 3; k++) acc[t][k] = 0.f;
    const float* vb = out + (size_t)b*VV*3;
    for (int v = ln; v < VV; v += 64) {
        const float x = vb[v*3+0], y = vb[v*3+1], z = vb[v*3+2];
#pragma unroll
        for (int t = 0; t < 7; t++) {
            if (t < jn) {
                const int jj = j0 + t;
                const float jr = (jj < 9) ? Je9[(size_t)jj*VV + v] : Jh[(size_t)(jj-9)*VV + v];
                acc[t][0] += jr*x; acc[t][1] += jr*y; acc[t][2] += jr*z;
            }
        }
    }
#pragma unroll
    for (int off = 1; off < 64; off <<= 1)
#pragma unroll
        for (int t = 0; t < 7; t++)
#pragma unroll
            for (int k = 0; k < 3; k++) acc[t][k] += __shfl_xor(acc[t][k], off);
    if (ln == 0)
#pragma unroll
        for (int t = 0; t < 7; t++)
            if (t < jn)
#pragma unroll
                for (int k = 0; k < 3; k++)
                    out[OUTJ + ((size_t)b*NJOUT + 35 + j0 + t)*3 + k] = acc[t][k];
    if (wv == 0 && ln < 33) {
        const int j = ln / 3, k = ln % 3;
        out[OUTJ + ((size_t)b*NJOUT + 24 + j)*3 + k] = vb[(size_t)eidx[j]*3 + k];
    }
}

extern "C" void kernel_launch(void* const* d_in, const int* in_sizes, int n_in,
                              void* d_out, int out_size, void* d_ws, size_t ws_size,
                              hipStream_t stream) {
    const float* betas = (const float*)d_in[0];
    const float* poses = (const float*)d_in[1];
    const int*   eidx  = (const int*)  d_in[2];
    const float* vt    = (const float*)d_in[3];
    const float* sd    = (const float*)d_in[4];
    const float* pd    = (const float*)d_in[5];
    const float* Jreg  = (const float*)d_in[6];
    const float* lbsw  = (const float*)d_in[7];
    const float* Je9   = (const float*)d_in[8];
    const float* Jh    = (const float*)d_in[9];
    float* out = (float*)d_out;
    float* ws  = (float*)d_ws;
    short* Ablk = (short*)((char*)d_ws + WS_ABLK_BYTES);
    short* Bblk = (short*)((char*)d_ws + WS_BBLK_BYTES);
    short* A2   = (short*)((char*)d_ws + WS_A2_BYTES);
    short* W2   = (short*)((char*)d_ws + WS_W2_BYTES);

    k_buildB  <<<dim3(NVT, NKC), dim3(256), 0, stream>>>(pd, sd, Bblk);
    k_buildW  <<<dim3(NVT),      dim3(64),  0, stream>>>(lbsw, W2);
    k_jointreg<<<dim3(72),       dim3(256), 0, stream>>>(Jreg, vt, sd, ws);
    k_batch   <<<dim3(1024),     dim3(64),  0, stream>>>(betas, poses, ws, Ablk, A2, out);
    k_fused   <<<dim3(NVT, 32),  dim3(256), 0, stream>>>(Ablk, Bblk, A2, W2, vt, out);
    k_joints  <<<dim3(1024),     dim3(256), 0, stream>>>(Je9, Jh, eidx, out);
}